// Round 4
// baseline (132.539 us; speedup 1.0000x reference)
//
#include <hip/hip_runtime.h>
#include <hip/hip_fp16.h>
#include <math.h>

#define NN 100000
#define NE 1600000
#define FIN 50
#define NC 16
#define TILE_NODES 32

#define NPB 256                       // nodes per bucket
#define NB  ((NN + NPB - 1) / NPB)    // 391 buckets
#define CAP 4608                      // slots per bucket (mean 4092 + 8 sigma)
#define NBLK_PART 512                 // was 256: 2x place waves (round-3 lesson:
                                      // place tail runs at 1 wave/SIMD)
#define EPB (NE / NBLK_PART)          // 3125 edges / partition block (exact)
#define NBLK_LIN 512

// ---------------------------------------------------------------------------
// Fused front-end. Blocks [0, NBLK_PART): placement of edges into
// fixed-capacity bucket regions via in-LDS counting sort by bucket + a
// coalesced output pass (round-1 lesson: thread-order scatter = 1 line/edge,
// WRITE 72MB). Round-3 lesson: at NBLK_PART=256 the place role tail ran at
// 1 block/CU = 1 wave/SIMD, latency-bound at ~33us regardless of write
// pattern. Now 512 place blocks (25KB LDS each) -> whole 1024-block grid
// co-resident at 4 blocks/CU, place at 8 waves/CU. Run length 8 edges
// (32B) keeps write amp ~2x on the 6.4MB payload.
// Blocks [NBLK_PART, +NBLK_LIN): y_l = x@W_l^T (f16) and self = x@W_r^T
// (f32). Roles overlap: cost = max, not sum.
// ---------------------------------------------------------------------------
__global__ __launch_bounds__(256) void fused_front(
    const float* __restrict__ x,
    const float* __restrict__ W_l,
    const float* __restrict__ W_r,
    const int* __restrict__ ei,       // [2, NE]
    int* __restrict__ gcur_s,         // [NB*16] cursors (zeroed)
    unsigned int* __restrict__ buf,   // [NB*CAP]
    __half2* __restrict__ y_l,        // [NN*8]
    float* __restrict__ self_out)     // [NN*NC]
{
    // place: h/lstart/lcur/gbase 4*391*4=6256B | slist 3125*4=12500B |
    //        bid u16 3125*2=6250B  = 25006B.   lin: 12.8KB (reuses front).
    __shared__ __align__(16) char smem[25024];
    __shared__ int wsum[4];
    const int tid = threadIdx.x;

    if (blockIdx.x < NBLK_PART) {
        // ---- place role ----
        int* h      = (int*)smem;                 // [NB] histogram
        int* lstart = h + NB;                     // [NB] local sorted start
        int* lcur   = lstart + NB;                // [NB] scatter cursor
        int* gbase  = lcur + NB;                  // [NB] global reserved base
        unsigned* slist = (unsigned*)(gbase + NB);            // [EPB]
        unsigned short* bid = (unsigned short*)(slist + EPB); // [EPB]

        for (int i = tid; i < NB; i += 256) h[i] = 0;
        __syncthreads();

        const int e0 = blockIdx.x * EPB;          // EPB divides NE exactly

        // pass 1: histogram over buckets (LDS int atomics, targets only)
        for (int i = tid; i < EPB; i += 256)
            atomicAdd(&h[((unsigned)ei[NE + e0 + i]) >> 8], 1);
        __syncthreads();

        // pass 2: exclusive scan of h[0..NB) -> lstart. Thread t owns
        // buckets {2t, 2t+1}; 256-wide scan of pair-sums (wave scan + fixup).
        {
            const int i0 = 2 * tid, i1 = 2 * tid + 1;
            const int h0 = (i0 < NB) ? h[i0] : 0;
            const int h1 = (i1 < NB) ? h[i1] : 0;
            const int own = h0 + h1;
            int incl = own;
#pragma unroll
            for (int off = 1; off < 64; off <<= 1) {
                int t = __shfl_up(incl, off, 64);
                if ((tid & 63) >= off) incl += t;
            }
            if ((tid & 63) == 63) wsum[tid >> 6] = incl;
            __syncthreads();
            const int w = tid >> 6;
            int pfx = 0;
            if (w > 0) pfx += wsum[0];
            if (w > 1) pfx += wsum[1];
            if (w > 2) pfx += wsum[2];
            const int excl = pfx + incl - own;
            if (i0 < NB) { lstart[i0] = excl; lcur[i0] = excl; }
            if (i1 < NB) { lstart[i1] = excl + h0; lcur[i1] = excl + h0; }
        }
        __syncthreads();

        // pass 3: one global cursor reservation per nonempty bucket
        for (int b = tid; b < NB; b += 256)
            gbase[b] = h[b] ? atomicAdd(&gcur_s[b * 16], h[b]) : 0;

        // pass 4: counting-sort scatter into LDS (1 LDS atomic + 2 LDS
        // writes per edge — cheap vs. a scattered global line each)
        for (int i = tid; i < EPB; i += 256) {
            const int s = ei[e0 + i];
            const int t = ei[NE + e0 + i];
            const int b = ((unsigned)t) >> 8;
            const int pos = atomicAdd(&lcur[b], 1);
            slist[pos] = (unsigned)s | ((unsigned)(t & 255) << 17);
            bid[pos] = (unsigned short)b;
        }
        __syncthreads();

        // pass 5: coalesced output — consecutive i => consecutive global
        // addresses within each ~8-edge (32B) bucket run
        for (int i = tid; i < EPB; i += 256) {
            const unsigned v = slist[i];
            const int b = bid[i];
            const int goff = gbase[b] + (i - lstart[b]);
            if (goff < CAP)
                buf[(size_t)b * CAP + goff] = v;
        }
    } else {
        // ---- lin role ----
        float* sWl = (float*)smem;            // [NC*FIN]
        float* sWr = sWl + NC * FIN;          // [NC*FIN]
        float* sx  = sWr + NC * FIN;          // [TILE_NODES*FIN]

        for (int i = tid; i < NC * FIN; i += 256) {
            sWl[i] = W_l[i];
            sWr[i] = W_r[i];
        }

        const int bidx = blockIdx.x - NBLK_PART;
        const int ntiles = NN / TILE_NODES;   // 3125 exact: no tail tile
        const int ln = tid >> 3;
        const int cp = tid & 7;

        for (int tile = bidx; tile < ntiles; tile += NBLK_LIN) {
            __syncthreads();
            const int node0 = tile * TILE_NODES;
            // x tile is contiguous [node0*50, node0*50+1600) and 16B-aligned
            // (node0*200 % 16 == 0): float4-coalesced stage
            {
                const float4* xs = (const float4*)(x + (size_t)node0 * FIN);
                float4* sx4 = (float4*)sx;
                for (int j = tid; j < TILE_NODES * FIN / 4; j += 256)
                    sx4[j] = xs[j];
            }
            __syncthreads();

            const int n = node0 + ln;
            const float* xr = &sx[ln * FIN];
            const float* w0 = &sWl[(2 * cp) * FIN];
            const float* w1 = w0 + FIN;
            const float* u0 = &sWr[(2 * cp) * FIN];
            const float* u1 = u0 + FIN;

            float a0 = 0.f, a1 = 0.f, r0 = 0.f, r1 = 0.f;
#pragma unroll
            for (int k = 0; k < FIN; ++k) {
                float xv = xr[k];
                a0 = fmaf(xv, w0[k], a0);
                a1 = fmaf(xv, w1[k], a1);
                r0 = fmaf(xv, u0[k], r0);
                r1 = fmaf(xv, u1[k], r1);
            }
            y_l[n * 8 + cp] = __floats2half2_rn(a0, a1);
            ((float2*)self_out)[n * 8 + cp] = make_float2(r0, r1);
        }
    }
}

// ---------------------------------------------------------------------------
// Aggregation (round-0 proven config): one 1024-thread block per bucket
// (256 nodes). In-LDS counting sort by local target, 256-wide scan,
// contention-free register segment-reduce (tid = tl*4+q, quad covers 16
// classes via uint2 loads), fused mean/bias/self/log_softmax epilogue.
// ---------------------------------------------------------------------------
__global__ __launch_bounds__(1024) void agg_kernel(
    const int* __restrict__ gcur_s,
    const unsigned int* __restrict__ buf,
    const uint2* __restrict__ y2,     // y_l as uint2[NN*4]
    const float* __restrict__ b_l,
    float* __restrict__ logp,
    float* __restrict__ outv)         // self (f32) on entry, final out on exit
{
    __shared__ unsigned slist[CAP];   // 18.4 KB
    __shared__ int lcnt[NPB];
    __shared__ int scur[NPB];
    __shared__ int sstart[NPB];
    __shared__ int wsum[4];
    __shared__ float sb[NC];

    const int tid = threadIdx.x;
    if (tid < NPB) lcnt[tid] = 0;
    if (tid < NC) sb[tid] = b_l[tid];
    __syncthreads();

    const int b = blockIdx.x;
    int cnt = gcur_s[b * 16];
    if (cnt > CAP) cnt = CAP;
    const size_t base = (size_t)b * CAP;

    // pass 1: per-local-node counts (1 LDS int atomic per edge)
    for (int i = tid; i < cnt; i += 1024)
        atomicAdd(&lcnt[buf[base + i] >> 17], 1);
    __syncthreads();

    // pass 2: 256-wide exclusive scan (4 waves scan 64 each, then fixup)
    int own = 0, incl = 0;
    if (tid < NPB) {
        own = lcnt[tid];
        incl = own;
#pragma unroll
        for (int off = 1; off < 64; off <<= 1) {
            int t = __shfl_up(incl, off, 64);
            if ((tid & 63) >= off) incl += t;
        }
        if ((tid & 63) == 63) wsum[tid >> 6] = incl;
    }
    __syncthreads();
    if (tid < NPB) {
        const int w = tid >> 6;
        int pfx = 0;
        if (w > 0) pfx += wsum[0];
        if (w > 1) pfx += wsum[1];
        if (w > 2) pfx += wsum[2];
        const int st = pfx + incl - own;
        sstart[tid] = st;
        scur[tid]   = st;
    }
    __syncthreads();

    // pass 3: scatter src ids into sorted slots (1 atomic + 1 write per edge)
    for (int i = tid; i < cnt; i += 1024) {
        unsigned v = buf[base + i];
        int pos = atomicAdd(&scur[v >> 17], 1);
        slist[pos] = v & 0x1FFFF;
    }
    __syncthreads();

    // pass 4: segment reduce, registers only. tid = tl*4 + q.
    const int tl = tid >> 2;
    const int q  = tid & 3;
    const int n  = b * NPB + tl;
    if (n >= NN) return;

    const int seg0 = sstart[tl];
    const int deg  = lcnt[tl];
    const int seg1 = seg0 + deg;

    float a0 = 0.f, a1 = 0.f, a2 = 0.f, a3 = 0.f;
    int i = seg0;
    for (; i + 2 <= seg1; i += 2) {
        int sA = slist[i];
        int sB = slist[i + 1];
        uint2 qa = y2[sA * 4 + q];
        uint2 qb = y2[sB * 4 + q];
        float2 fa = __half22float2(__builtin_bit_cast(__half2, qa.x));
        float2 fb = __half22float2(__builtin_bit_cast(__half2, qa.y));
        float2 fc = __half22float2(__builtin_bit_cast(__half2, qb.x));
        float2 fd = __half22float2(__builtin_bit_cast(__half2, qb.y));
        a0 += fa.x + fc.x;
        a1 += fa.y + fc.y;
        a2 += fb.x + fd.x;
        a3 += fb.y + fd.y;
    }
    if (i < seg1) {
        uint2 qa = y2[slist[i] * 4 + q];
        float2 fa = __half22float2(__builtin_bit_cast(__half2, qa.x));
        float2 fb = __half22float2(__builtin_bit_cast(__half2, qa.y));
        a0 += fa.x; a1 += fa.y; a2 += fb.x; a3 += fb.y;
    }

    // pass 5: fused epilogue, width-4 shfl reductions
    const float4 sf = ((const float4*)(outv + (size_t)n * NC))[q];
    float inv = 1.0f / fmaxf((float)deg, 1.0f);
    float v0 = a0 * inv + sb[4 * q + 0] + sf.x;
    float v1 = a1 * inv + sb[4 * q + 1] + sf.y;
    float v2 = a2 * inv + sb[4 * q + 2] + sf.z;
    float v3 = a3 * inv + sb[4 * q + 3] + sf.w;

    float m = fmaxf(fmaxf(v0, v1), fmaxf(v2, v3));
    m = fmaxf(m, __shfl_xor(m, 1, 4));
    m = fmaxf(m, __shfl_xor(m, 2, 4));
    float es = expf(v0 - m) + expf(v1 - m) + expf(v2 - m) + expf(v3 - m);
    es += __shfl_xor(es, 1, 4);
    es += __shfl_xor(es, 2, 4);
    float lse = m + logf(es);

    ((float4*)(outv + (size_t)n * NC))[q] = make_float4(v0, v1, v2, v3);
    ((float4*)(logp + (size_t)n * NC))[q] =
        make_float4(v0 - lse, v1 - lse, v2 - lse, v3 - lse);
}

extern "C" void kernel_launch(void* const* d_in, const int* in_sizes, int n_in,
                              void* d_out, int out_size, void* d_ws, size_t ws_size,
                              hipStream_t stream) {
    const float* x   = (const float*)d_in[0];
    const int*   ei  = (const int*)d_in[1];
    const float* W_l = (const float*)d_in[2];
    const float* b_l = (const float*)d_in[3];
    const float* W_r = (const float*)d_in[4];

    float* logp = (float*)d_out;                    // [NN*NC]
    float* outv = (float*)d_out + (size_t)NN * NC;  // [NN*NC], self scratch

    // ws: y_l half2[NN*8] (3.2MB) | buf u32[NB*CAP] (7.2MB) | gcur_s[NB*16] (25KB)
    __half2* y_l  = (__half2*)d_ws;
    unsigned* buf = (unsigned*)(y_l + (size_t)NN * 8);
    int* gcur_s   = (int*)(buf + (size_t)NB * CAP);

    hipMemsetAsync(gcur_s, 0, (size_t)NB * 16 * sizeof(int), stream);

    fused_front<<<NBLK_PART + NBLK_LIN, 256, 0, stream>>>(
        x, W_l, W_r, ei, gcur_s, buf, y_l, outv);
    agg_kernel<<<NB, 1024, 0, stream>>>(gcur_s, buf, (const uint2*)y_l, b_l, logp, outv);
}

// Round 5
// 126.626 us; speedup vs baseline: 1.0467x; 1.0467x over previous
//
#include <hip/hip_runtime.h>
#include <hip/hip_fp16.h>
#include <math.h>

#define NN 100000
#define NE 1600000
#define FIN 50
#define NC 16

#define NPB 256                       // nodes per bucket
#define NB  ((NN + NPB - 1) / NPB)    // 391 buckets
#define CAP 4608                      // slots per bucket (mean 4092 + 8 sigma)
#define NBLK_PART 256                 // place blocks (1024 threads each)
#define EPB (NE / NBLK_PART)          // 6250 edges/block -> run length 16
#define KED ((EPB + 1023) / 1024)     // 7 register-cached edges/thread
#define NBLK_LIN 256                  // lin blocks (1024 threads each)
#define LTILE 128                     // lin nodes/tile

// ---------------------------------------------------------------------------
// Fused front-end, 512 blocks x 1024 threads (2 blocks/CU, 32 waves/CU =
// 100% wave slots during overlap). Blocks [0,256): place role — in-LDS
// counting sort by bucket (run length 16 = 64B coalesced output runs,
// round-1 lesson) at 16 waves/CU (2x round-4, round-3/4 lesson: place tail
// was wave-starved). ei register-cached: read ONCE (12.8MB not 19.2MB).
// Blocks [256,512): lin role — y_l = x@W_l^T (f16), self = x@W_r^T (f32),
// 128-node tiles. Roles overlap: cost = max, not sum.
// ---------------------------------------------------------------------------
__global__ __launch_bounds__(1024) void fused_front(
    const float* __restrict__ x,
    const float* __restrict__ W_l,
    const float* __restrict__ W_r,
    const int* __restrict__ ei,       // [2, NE]
    int* __restrict__ gcur_s,         // [NB*16] cursors (zeroed)
    unsigned int* __restrict__ buf,   // [NB*CAP]
    __half2* __restrict__ y_l,        // [NN*8]
    float* __restrict__ self_out)     // [NN*NC]
{
    // place: h/lstart/lcur/gbase 4*391*4=6256B | slist 6250*4=25000B |
    //        bid u16 6250*2=12500B = 43756B.
    // lin:   sWl+sWr 6400B | sx 128*50*4=25600B = 32000B.
    __shared__ __align__(16) char smem[43776];
    __shared__ int wsum[8];
    const int tid = threadIdx.x;

    if (blockIdx.x < NBLK_PART) {
        // ---- place role ----
        int* h      = (int*)smem;                 // [NB] histogram
        int* lstart = h + NB;                     // [NB] local sorted start
        int* lcur   = lstart + NB;                // [NB] scatter cursor
        int* gbase  = lcur + NB;                  // [NB] global reserved base
        unsigned* slist = (unsigned*)(gbase + NB);            // [EPB]
        unsigned short* bid = (unsigned short*)(slist + EPB); // [EPB]

        if (tid < NB) h[tid] = 0;

        const int e0 = blockIdx.x * EPB;          // EPB divides NE exactly

        // register-cache this thread's edges: ei read ONCE (static unroll
        // so er[] stays in VGPRs — rule #20)
        int2 er[KED];
#pragma unroll
        for (int k = 0; k < KED; ++k) {
            const int e = tid + (k << 10);
            if (e < EPB) { er[k].x = ei[e0 + e]; er[k].y = ei[NE + e0 + e]; }
        }
        __syncthreads();

        // pass 1: histogram over buckets (LDS int atomics, from registers)
#pragma unroll
        for (int k = 0; k < KED; ++k) {
            const int e = tid + (k << 10);
            if (e < EPB) atomicAdd(&h[((unsigned)er[k].y) >> 8], 1);
        }
        __syncthreads();

        // pass 2: exclusive scan of h[0..391) — first 391 threads own one
        // bucket each; 7 wave-scans + cross-wave fixup
        int own = 0, incl = 0;
        if (tid < NB) {
            own = h[tid];
            incl = own;
#pragma unroll
            for (int off = 1; off < 64; off <<= 1) {
                int t = __shfl_up(incl, off, 64);
                if ((tid & 63) >= off) incl += t;
            }
            if ((tid & 63) == 63) wsum[tid >> 6] = incl;
        }
        __syncthreads();
        if (tid < NB) {
            const int w = tid >> 6;
            int pfx = 0;
#pragma unroll
            for (int j = 0; j < 6; ++j)
                if (j < w) pfx += wsum[j];
            const int st = pfx + incl - own;
            lstart[tid] = st;
            lcur[tid]   = st;
            // pass 3 fused: one global cursor reservation per nonempty bucket
            gbase[tid] = own ? atomicAdd(&gcur_s[tid * 16], own) : 0;
        }
        __syncthreads();

        // pass 4: counting-sort scatter into LDS (1 LDS atomic + 2 LDS writes)
#pragma unroll
        for (int k = 0; k < KED; ++k) {
            const int e = tid + (k << 10);
            if (e < EPB) {
                const int b = ((unsigned)er[k].y) >> 8;
                const int pos = atomicAdd(&lcur[b], 1);
                slist[pos] = (unsigned)er[k].x | ((unsigned)(er[k].y & 255) << 17);
                bid[pos] = (unsigned short)b;
            }
        }
        __syncthreads();

        // pass 5: coalesced output — consecutive i => consecutive global
        // addresses within each ~16-edge (64B) bucket run
#pragma unroll
        for (int k = 0; k < KED; ++k) {
            const int i = tid + (k << 10);
            if (i < EPB) {
                const unsigned v = slist[i];
                const int b = bid[i];
                const int goff = gbase[b] + (i - lstart[b]);
                if (goff < CAP)
                    buf[(size_t)b * CAP + goff] = v;
            }
        }
    } else {
        // ---- lin role ----
        float* sWl = (float*)smem;            // [NC*FIN]
        float* sWr = sWl + NC * FIN;          // [NC*FIN]
        float* sx  = sWr + NC * FIN;          // [LTILE*FIN]

        if (tid < NC * FIN) {
            sWl[tid] = W_l[tid];
            sWr[tid] = W_r[tid];
        }

        const int bidx = blockIdx.x - NBLK_PART;
        const int ntiles = (NN + LTILE - 1) / LTILE;  // 782 (tail = 32 nodes)
        const int ln = tid >> 3;
        const int cp = tid & 7;

        for (int tile = bidx; tile < ntiles; tile += NBLK_LIN) {
            __syncthreads();
            const int node0 = tile * LTILE;
            const int nn = min(LTILE, NN - node0);
            const int nf4 = nn * FIN / 4;     // 1600 full / 400 tail, exact
            {
                const float4* xs = (const float4*)(x + (size_t)node0 * FIN);
                float4* sx4 = (float4*)sx;
                for (int j = tid; j < nf4; j += 1024)
                    sx4[j] = xs[j];
            }
            __syncthreads();

            const int n = node0 + ln;
            if (n >= NN) continue;

            const float* xr = &sx[ln * FIN];
            const float* w0 = &sWl[(2 * cp) * FIN];
            const float* w1 = w0 + FIN;
            const float* u0 = &sWr[(2 * cp) * FIN];
            const float* u1 = u0 + FIN;

            float a0 = 0.f, a1 = 0.f, r0 = 0.f, r1 = 0.f;
#pragma unroll
            for (int k = 0; k < FIN; ++k) {
                float xv = xr[k];
                a0 = fmaf(xv, w0[k], a0);
                a1 = fmaf(xv, w1[k], a1);
                r0 = fmaf(xv, u0[k], r0);
                r1 = fmaf(xv, u1[k], r1);
            }
            y_l[n * 8 + cp] = __floats2half2_rn(a0, a1);
            ((float2*)self_out)[n * 8 + cp] = make_float2(r0, r1);
        }
    }
}

// ---------------------------------------------------------------------------
// Aggregation: one 1024-thread block per bucket (256 nodes). buf register-
// cached (read ONCE instead of twice). In-LDS counting sort by local target,
// 256-wide scan, contention-free register segment-reduce (tid = tl*4+q, quad
// covers 16 classes via uint2 loads, 4-wide unrolled for gather MLP), fused
// mean/bias/self/log_softmax epilogue.
// ---------------------------------------------------------------------------
#define KAGG ((CAP + 1023) / 1024)    // 5 register-cached edges/thread

__global__ __launch_bounds__(1024) void agg_kernel(
    const int* __restrict__ gcur_s,
    const unsigned int* __restrict__ buf,
    const uint2* __restrict__ y2,     // y_l as uint2[NN*4]
    const float* __restrict__ b_l,
    float* __restrict__ logp,
    float* __restrict__ outv)         // self (f32) on entry, final out on exit
{
    __shared__ unsigned slist[CAP];   // 18.4 KB
    __shared__ int lcnt[NPB];
    __shared__ int scur[NPB];
    __shared__ int sstart[NPB];
    __shared__ int wsum[4];
    __shared__ float sb[NC];

    const int tid = threadIdx.x;
    if (tid < NPB) lcnt[tid] = 0;
    if (tid < NC) sb[tid] = b_l[tid];
    __syncthreads();

    const int b = blockIdx.x;
    int cnt = gcur_s[b * 16];
    if (cnt > CAP) cnt = CAP;
    const size_t base = (size_t)b * CAP;

    // register-cache this block's bucket slice: buf read ONCE
    unsigned ev[KAGG];
#pragma unroll
    for (int k = 0; k < KAGG; ++k) {
        const int i = tid + (k << 10);
        if (i < cnt) ev[k] = buf[base + i];
    }

    // pass 1: per-local-node counts (1 LDS int atomic per edge)
#pragma unroll
    for (int k = 0; k < KAGG; ++k) {
        const int i = tid + (k << 10);
        if (i < cnt) atomicAdd(&lcnt[ev[k] >> 17], 1);
    }
    __syncthreads();

    // pass 2: 256-wide exclusive scan (4 waves scan 64 each, then fixup)
    int own = 0, incl = 0;
    if (tid < NPB) {
        own = lcnt[tid];
        incl = own;
#pragma unroll
        for (int off = 1; off < 64; off <<= 1) {
            int t = __shfl_up(incl, off, 64);
            if ((tid & 63) >= off) incl += t;
        }
        if ((tid & 63) == 63) wsum[tid >> 6] = incl;
    }
    __syncthreads();
    if (tid < NPB) {
        const int w = tid >> 6;
        int pfx = 0;
        if (w > 0) pfx += wsum[0];
        if (w > 1) pfx += wsum[1];
        if (w > 2) pfx += wsum[2];
        const int st = pfx + incl - own;
        sstart[tid] = st;
        scur[tid]   = st;
    }
    __syncthreads();

    // pass 3: scatter src ids into sorted slots (from registers)
#pragma unroll
    for (int k = 0; k < KAGG; ++k) {
        const int i = tid + (k << 10);
        if (i < cnt) {
            const unsigned v = ev[k];
            const int pos = atomicAdd(&scur[v >> 17], 1);
            slist[pos] = v & 0x1FFFF;
        }
    }
    __syncthreads();

    // pass 4: segment reduce, registers only. tid = tl*4 + q. 4-wide unroll
    // keeps 4 independent ~600cy cross-XCD gathers in flight.
    const int tl = tid >> 2;
    const int q  = tid & 3;
    const int n  = b * NPB + tl;
    if (n >= NN) return;

    const int seg0 = sstart[tl];
    const int deg  = lcnt[tl];
    const int seg1 = seg0 + deg;

    float a0 = 0.f, a1 = 0.f, a2 = 0.f, a3 = 0.f;
    int i = seg0;
    for (; i + 4 <= seg1; i += 4) {
        const int sA = slist[i];
        const int sB = slist[i + 1];
        const int sC = slist[i + 2];
        const int sD = slist[i + 3];
        uint2 qa = y2[sA * 4 + q];
        uint2 qb = y2[sB * 4 + q];
        uint2 qc = y2[sC * 4 + q];
        uint2 qd = y2[sD * 4 + q];
        float2 f0 = __half22float2(__builtin_bit_cast(__half2, qa.x));
        float2 f1 = __half22float2(__builtin_bit_cast(__half2, qa.y));
        float2 f2 = __half22float2(__builtin_bit_cast(__half2, qb.x));
        float2 f3 = __half22float2(__builtin_bit_cast(__half2, qb.y));
        float2 f4 = __half22float2(__builtin_bit_cast(__half2, qc.x));
        float2 f5 = __half22float2(__builtin_bit_cast(__half2, qc.y));
        float2 f6 = __half22float2(__builtin_bit_cast(__half2, qd.x));
        float2 f7 = __half22float2(__builtin_bit_cast(__half2, qd.y));
        a0 += (f0.x + f2.x) + (f4.x + f6.x);
        a1 += (f0.y + f2.y) + (f4.y + f6.y);
        a2 += (f1.x + f3.x) + (f5.x + f7.x);
        a3 += (f1.y + f3.y) + (f5.y + f7.y);
    }
    for (; i < seg1; ++i) {
        uint2 qa = y2[slist[i] * 4 + q];
        float2 f0 = __half22float2(__builtin_bit_cast(__half2, qa.x));
        float2 f1 = __half22float2(__builtin_bit_cast(__half2, qa.y));
        a0 += f0.x; a1 += f0.y; a2 += f1.x; a3 += f1.y;
    }

    // pass 5: fused epilogue, width-4 shfl reductions
    const float4 sf = ((const float4*)(outv + (size_t)n * NC))[q];
    float inv = 1.0f / fmaxf((float)deg, 1.0f);
    float v0 = a0 * inv + sb[4 * q + 0] + sf.x;
    float v1 = a1 * inv + sb[4 * q + 1] + sf.y;
    float v2 = a2 * inv + sb[4 * q + 2] + sf.z;
    float v3 = a3 * inv + sb[4 * q + 3] + sf.w;

    float m = fmaxf(fmaxf(v0, v1), fmaxf(v2, v3));
    m = fmaxf(m, __shfl_xor(m, 1, 4));
    m = fmaxf(m, __shfl_xor(m, 2, 4));
    float es = expf(v0 - m) + expf(v1 - m) + expf(v2 - m) + expf(v3 - m);
    es += __shfl_xor(es, 1, 4);
    es += __shfl_xor(es, 2, 4);
    float lse = m + logf(es);

    ((float4*)(outv + (size_t)n * NC))[q] = make_float4(v0, v1, v2, v3);
    ((float4*)(logp + (size_t)n * NC))[q] =
        make_float4(v0 - lse, v1 - lse, v2 - lse, v3 - lse);
}

extern "C" void kernel_launch(void* const* d_in, const int* in_sizes, int n_in,
                              void* d_out, int out_size, void* d_ws, size_t ws_size,
                              hipStream_t stream) {
    const float* x   = (const float*)d_in[0];
    const int*   ei  = (const int*)d_in[1];
    const float* W_l = (const float*)d_in[2];
    const float* b_l = (const float*)d_in[3];
    const float* W_r = (const float*)d_in[4];

    float* logp = (float*)d_out;                    // [NN*NC]
    float* outv = (float*)d_out + (size_t)NN * NC;  // [NN*NC], self scratch

    // ws: y_l half2[NN*8] (3.2MB) | buf u32[NB*CAP] (7.2MB) | gcur_s[NB*16] (25KB)
    __half2* y_l  = (__half2*)d_ws;
    unsigned* buf = (unsigned*)(y_l + (size_t)NN * 8);
    int* gcur_s   = (int*)(buf + (size_t)NB * CAP);

    hipMemsetAsync(gcur_s, 0, (size_t)NB * 16 * sizeof(int), stream);

    fused_front<<<NBLK_PART + NBLK_LIN, 1024, 0, stream>>>(
        x, W_l, W_r, ei, gcur_s, buf, y_l, outv);
    agg_kernel<<<NB, 1024, 0, stream>>>(gcur_s, buf, (const uint2*)y_l, b_l, logp, outv);
}